// Round 2
// baseline (2227.252 us; speedup 1.0000x reference)
//
#include <hip/hip_runtime.h>
#include <hip/hip_bf16.h>

#define NN 100000
#define NE 1600000
#define FIN 128
#define HD 64
#define NB_SCAN 391   // ceil(NN/256)

// ---------------- degree / CSR build ----------------

__global__ void k_count(const int* __restrict__ col, int* __restrict__ deg){
    int e = blockIdx.x*256 + threadIdx.x;
    if(e < NE) atomicAdd(&deg[col[e]], 1);
}

__global__ void k_bsum(const int* __restrict__ deg, int* __restrict__ bsum){
    __shared__ int r[256];
    int t = threadIdx.x; int i = blockIdx.x*256 + t;
    r[t] = (i < NN) ? deg[i] : 0;
    __syncthreads();
    for(int off=128; off>0; off>>=1){ if(t<off) r[t]+=r[t+off]; __syncthreads(); }
    if(t==0) bsum[blockIdx.x] = r[0];
}

__global__ void k_top(int* __restrict__ bsum){
    __shared__ int s[512];
    int t = threadIdx.x;
    int v = (t < NB_SCAN) ? bsum[t] : 0;
    s[t] = v; __syncthreads();
    for(int off=1; off<512; off<<=1){
        int a = (t>=off)? s[t-off] : 0;
        __syncthreads();
        s[t] += a;
        __syncthreads();
    }
    if(t < NB_SCAN) bsum[t] = s[t] - v;   // exclusive scan of block sums
}

__global__ void k_scan(const int* __restrict__ deg, const int* __restrict__ bsum,
                       int* __restrict__ starts, int* __restrict__ cursor,
                       float* __restrict__ dinv){
    __shared__ int s[256];
    int t = threadIdx.x; int i = blockIdx.x*256 + t;
    int d = (i<NN)? deg[i] : 0;
    s[t] = d; __syncthreads();
    for(int off=1; off<256; off<<=1){
        int a = (t>=off)? s[t-off] : 0;
        __syncthreads();
        s[t] += a;
        __syncthreads();
    }
    if(i < NN){
        int st = bsum[blockIdx.x] + s[t] - d;   // exclusive
        starts[i] = st; cursor[i] = st;
        dinv[i] = rsqrtf((float)(d + 1));       // +1 self-loop
    }
}

__global__ void k_fill(const int* __restrict__ row, const int* __restrict__ col,
                       int* __restrict__ cursor, int* __restrict__ csr){
    int e = blockIdx.x*256 + threadIdx.x;
    if(e < NE){
        int c = col[e];
        int p = atomicAdd(&cursor[c], 1);
        csr[p] = row[e];
    }
}

// ---------------- encoder: relu(bn(x @ W + b)) ----------------
// wave per node, lane j = output feature
__global__ void __launch_bounds__(256) k_enc(const float* __restrict__ x,
                                             const float* __restrict__ Wf,
                                             const float* __restrict__ bias,
                                             const float* __restrict__ g,
                                             const float* __restrict__ beta,
                                             const float* __restrict__ mean,
                                             const float* __restrict__ var,
                                             float* __restrict__ out){
    __shared__ float xs[4][FIN];
    int t = threadIdx.x, w = t>>6, j = t&63;
    int n = blockIdx.x*4 + w;                // grid covers exactly NN (NN%4==0)
    const float* xr = x + (size_t)n*FIN;
    xs[w][j]    = xr[j];
    xs[w][j+64] = xr[j+64];
    __syncthreads();
    float acc = 0.f;
    const float4* xv = (const float4*)xs[w];
    #pragma unroll 8
    for(int kk=0; kk<FIN/4; kk++){
        float4 v = xv[kk];
        int k = kk*4;
        acc += v.x * Wf[(k+0)*64 + j];
        acc += v.y * Wf[(k+1)*64 + j];
        acc += v.z * Wf[(k+2)*64 + j];
        acc += v.w * Wf[(k+3)*64 + j];
    }
    float sc = g[j] * rsqrtf(var[j] + 1e-5f);
    float v = (acc + bias[j] - mean[j]) * sc + beta[j];
    out[(size_t)n*64 + j] = fmaxf(v, 0.f);
}

// ---------------- 64x64 linear: out = in @ W ----------------
__global__ void __launch_bounds__(256) k_lin64(const float* __restrict__ in,
                                               const float* __restrict__ Wf,
                                               float* __restrict__ out){
    __shared__ float xs[4][64];
    int t = threadIdx.x, w = t>>6, j = t&63;
    int n = blockIdx.x*4 + w;
    xs[w][j] = in[(size_t)n*64 + j];
    __syncthreads();
    float acc = 0.f;
    const float4* xv = (const float4*)xs[w];
    #pragma unroll 8
    for(int kk=0; kk<16; kk++){
        float4 v = xv[kk];
        int k = kk*4;
        acc += v.x * Wf[(k+0)*64 + j];
        acc += v.y * Wf[(k+1)*64 + j];
        acc += v.z * Wf[(k+2)*64 + j];
        acc += v.w * Wf[(k+3)*64 + j];
    }
    out[(size_t)n*64 + j] = acc;
}

// ---------------- GCN aggregation: relu(sum_in + self + b) ----------------
// wave per node n, lane f: out = dinv[n]*sum_e hw[row_e][f]*dinv[row_e] + hw[n][f]*dinv[n]^2 + b[f]
__global__ void __launch_bounds__(256) k_agg(const float* __restrict__ hw,
                                             const int* __restrict__ starts,
                                             const int* __restrict__ deg,
                                             const int* __restrict__ csr,
                                             const float* __restrict__ dinv,
                                             const float* __restrict__ bias,
                                             float* __restrict__ out){
    int t = threadIdx.x, w = t>>6, f = t&63;
    int n = blockIdx.x*4 + w;
    int s = starts[n], d = deg[n];
    float acc = 0.f;
    int i = 0;
    for(; i+1 < d; i += 2){                 // 2-way unroll for latency overlap
        int r0 = csr[s+i], r1 = csr[s+i+1];
        float v0 = hw[(size_t)r0*64 + f];
        float v1 = hw[(size_t)r1*64 + f];
        acc += v0 * dinv[r0];
        acc += v1 * dinv[r1];
    }
    if(i < d){
        int r0 = csr[s+i];
        acc += hw[(size_t)r0*64 + f] * dinv[r0];
    }
    float dn = dinv[n];
    float self = hw[(size_t)n*64 + f];
    float v = acc*dn + self*dn*dn + bias[f];
    out[(size_t)n*64 + f] = fmaxf(v, 0.f);
}

// ---------------- edge predictor ----------------
// wave per edge: hidden_j = relu(bn(cat(h[r],h[c]) @ W1 + b1)); pred = sigmoid(hidden . w2 + b2)
__global__ void __launch_bounds__(256) k_edge(const float* __restrict__ h,
                                              const int* __restrict__ row,
                                              const int* __restrict__ col,
                                              const float* __restrict__ W1f,
                                              const float* __restrict__ w2f,
                                              const float* __restrict__ b1,
                                              const float* __restrict__ g,
                                              const float* __restrict__ beta,
                                              const float* __restrict__ mean,
                                              const float* __restrict__ var,
                                              const float* __restrict__ b2,
                                              float* __restrict__ out){
    __shared__ float ef[4][128];
    int t = threadIdx.x, w = t>>6, j = t&63;
    int e = blockIdx.x*4 + w;                // grid covers exactly NE (NE%4==0)
    int r = row[e], c = col[e];
    ef[w][j]    = h[(size_t)r*64 + j];
    ef[w][j+64] = h[(size_t)c*64 + j];
    __syncthreads();
    float acc = 0.f;
    const float4* xv = (const float4*)ef[w];
    #pragma unroll 8
    for(int kk=0; kk<32; kk++){
        float4 v = xv[kk];
        int k = kk*4;
        acc += v.x * W1f[(k+0)*64 + j];
        acc += v.y * W1f[(k+1)*64 + j];
        acc += v.z * W1f[(k+2)*64 + j];
        acc += v.w * W1f[(k+3)*64 + j];
    }
    float sc = g[j] * rsqrtf(var[j] + 1e-5f);
    float v = (acc + b1[j] - mean[j]) * sc + beta[j];
    v = fmaxf(v, 0.f);
    float p = v * w2f[j];
    #pragma unroll
    for(int off=32; off>0; off>>=1) p += __shfl_down(p, off, 64);
    if(j == 0){
        float z = p + b2[0];
        out[e] = 1.f / (1.f + __expf(-z));
    }
}

// ---------------- launch ----------------

extern "C" void kernel_launch(void* const* d_in, const int* in_sizes, int n_in,
                              void* d_out, int out_size, void* d_ws, size_t ws_size,
                              hipStream_t stream){
    const float* x   = (const float*)d_in[0];
    const int* ei    = (const int*)d_in[1];
    const int* row   = ei;
    const int* col   = ei + NE;
    const float* encW = (const float*)d_in[2],  *encB = (const float*)d_in[3];
    const float* encG = (const float*)d_in[4],  *encBe= (const float*)d_in[5];
    const float* encM = (const float*)d_in[6],  *encV = (const float*)d_in[7];
    const float* c1W  = (const float*)d_in[8],  *c1b  = (const float*)d_in[9];
    const float* c2W  = (const float*)d_in[10], *c2b  = (const float*)d_in[11];
    const float* ep1W = (const float*)d_in[12], *ep1b = (const float*)d_in[13];
    const float* epG  = (const float*)d_in[14], *epBe = (const float*)d_in[15];
    const float* epM  = (const float*)d_in[16], *epV  = (const float*)d_in[17];
    const float* ep2W = (const float*)d_in[18], *ep2b = (const float*)d_in[19];

    char* wsc = (char*)d_ws;
    size_t o = 0;
    auto alloc = [&](size_t bytes)->void*{
        void* p = wsc + o; o += (bytes + 255) & ~(size_t)255; return p;
    };
    int*   deg    = (int*)  alloc((size_t)NN*4);
    int*   starts = (int*)  alloc((size_t)NN*4);
    int*   cursor = (int*)  alloc((size_t)NN*4);
    int*   bsum   = (int*)  alloc(1024*4);
    int*   csr    = (int*)  alloc((size_t)NE*4);
    float* dinv   = (float*)alloc((size_t)NN*4);
    float* bufA   = (float*)alloc((size_t)NN*64*4);
    float* bufB   = (float*)alloc((size_t)NN*64*4);
    // total ~59 MB of d_ws

    float* outp = (float*)d_out;               // [NN*64] node emb | [NE] edge preds
    float* node_out = outp;
    float* edge_out = outp + (size_t)NN*64;

    hipMemsetAsync(deg, 0, (size_t)NN*4, stream);
    k_count<<<(NE+255)/256, 256, 0, stream>>>(col, deg);
    k_bsum <<<NB_SCAN,      256, 0, stream>>>(deg, bsum);
    k_top  <<<1,            512, 0, stream>>>(bsum);
    k_scan <<<NB_SCAN,      256, 0, stream>>>(deg, bsum, starts, cursor, dinv);
    k_fill <<<(NE+255)/256, 256, 0, stream>>>(row, col, cursor, csr);

    k_enc  <<<NN/4, 256, 0, stream>>>(x, encW, encB, encG, encBe, encM, encV, bufA);

    k_lin64<<<NN/4, 256, 0, stream>>>(bufA, c1W, bufB);
    k_agg  <<<NN/4, 256, 0, stream>>>(bufB, starts, deg, csr, dinv, c1b, bufA);

    k_lin64<<<NN/4, 256, 0, stream>>>(bufA, c2W, bufB);
    k_agg  <<<NN/4, 256, 0, stream>>>(bufB, starts, deg, csr, dinv, c2b, node_out);

    k_edge <<<NE/4, 256, 0, stream>>>(node_out, row, col, ep1W, ep2W,
                                      ep1b, epG, epBe, epM, epV, ep2b,
                                      edge_out);
}

// Round 3
// 1001.117 us; speedup vs baseline: 2.2248x; 2.2248x over previous
//
#include <hip/hip_runtime.h>
#include <hip/hip_bf16.h>

#define NN 100000
#define NE 1600000
#define FIN 128
#define HD 64
#define NB_SCAN 391   // ceil(NN/256)

// ---------------- degree / CSR build ----------------

__global__ void k_count(const int* __restrict__ col, int* __restrict__ deg){
    int e = blockIdx.x*256 + threadIdx.x;
    if(e < NE) atomicAdd(&deg[col[e]], 1);
}

__global__ void k_bsum(const int* __restrict__ deg, int* __restrict__ bsum){
    __shared__ int r[256];
    int t = threadIdx.x; int i = blockIdx.x*256 + t;
    r[t] = (i < NN) ? deg[i] : 0;
    __syncthreads();
    for(int off=128; off>0; off>>=1){ if(t<off) r[t]+=r[t+off]; __syncthreads(); }
    if(t==0) bsum[blockIdx.x] = r[0];
}

__global__ void k_top(int* __restrict__ bsum){
    __shared__ int s[512];
    int t = threadIdx.x;
    int v = (t < NB_SCAN) ? bsum[t] : 0;
    s[t] = v; __syncthreads();
    for(int off=1; off<512; off<<=1){
        int a = (t>=off)? s[t-off] : 0;
        __syncthreads();
        s[t] += a;
        __syncthreads();
    }
    if(t < NB_SCAN) bsum[t] = s[t] - v;   // exclusive scan of block sums
}

__global__ void k_scan(const int* __restrict__ deg, const int* __restrict__ bsum,
                       int* __restrict__ starts, int* __restrict__ cursor,
                       float* __restrict__ dinv){
    __shared__ int s[256];
    int t = threadIdx.x; int i = blockIdx.x*256 + t;
    int d = (i<NN)? deg[i] : 0;
    s[t] = d; __syncthreads();
    for(int off=1; off<256; off<<=1){
        int a = (t>=off)? s[t-off] : 0;
        __syncthreads();
        s[t] += a;
        __syncthreads();
    }
    if(i < NN){
        int st = bsum[blockIdx.x] + s[t] - d;   // exclusive
        starts[i] = st; cursor[i] = st;
        dinv[i] = rsqrtf((float)(d + 1));       // +1 self-loop
    }
}

__global__ void k_fill(const int* __restrict__ row, const int* __restrict__ col,
                       int* __restrict__ cursor, int* __restrict__ csr){
    int e = blockIdx.x*256 + threadIdx.x;
    if(e < NE){
        int c = col[e];
        int p = atomicAdd(&cursor[c], 1);
        csr[p] = row[e];
    }
}

// ---------------- BN constant folding ----------------
// foldEnc[0:64]=s, foldEnc[64:128]=cst  (enc:  relu(acc*s + cst))
// foldPre[0:128]=S (s duplicated), foldPre[128:256]=C (cst for A half, 0 for B half)
__global__ void k_const(const float* __restrict__ encB, const float* __restrict__ encG,
                        const float* __restrict__ encBe, const float* __restrict__ encM,
                        const float* __restrict__ encV,
                        const float* __restrict__ ep1b, const float* __restrict__ epG,
                        const float* __restrict__ epBe, const float* __restrict__ epM,
                        const float* __restrict__ epV,
                        float* __restrict__ foldEnc, float* __restrict__ foldPre){
    int j = threadIdx.x;
    if(j < 64){
        float s = encG[j]*rsqrtf(encV[j]+1e-5f);
        foldEnc[j]      = s;
        foldEnc[64+j]   = (encB[j]-encM[j])*s + encBe[j];
        float sp = epG[j]*rsqrtf(epV[j]+1e-5f);
        foldPre[j]      = sp;
        foldPre[64+j]   = sp;
        foldPre[128+j]  = sp*(ep1b[j]-epM[j]) + epBe[j];
        foldPre[192+j]  = 0.f;
    }
}

// ---------------- generic GEMV: thread-per-node, W staged in LDS ----------------
// out[n][jb*64+j] = epilogue( sum_k in[n][k] * W[k][jb*64+j] )
// PREMAP: W source is ep1W [128,64]; logical W[k][j] = j<64 ? ep1W[k][j] : ep1W[64+k][j-64]
template<int K, int JB, bool PREMAP, bool FOLD, bool RELU>
__global__ void __launch_bounds__(256) k_gemv(const float* __restrict__ in,
                                              const float* __restrict__ W,
                                              const float* __restrict__ fold,
                                              float* __restrict__ out){
    __shared__ float Ws[K*JB*64];
    __shared__ float Fs[2*JB*64];
    const int J = JB*64;
    for(int idx = threadIdx.x; idx < K*J; idx += 256){
        if(PREMAP){
            int k = idx / J, j = idx % J;   // J=128 here
            Ws[idx] = (j < 64) ? W[k*64 + j] : W[(64+k)*64 + (j-64)];
        } else {
            Ws[idx] = W[idx];
        }
    }
    if(FOLD){
        for(int idx = threadIdx.x; idx < 2*J; idx += 256) Fs[idx] = fold[idx];
    }
    __syncthreads();
    int n = blockIdx.x*256 + threadIdx.x;
    if(n >= NN) return;
    const float4* x4 = (const float4*)(in + (size_t)n*K);
    for(int jb = 0; jb < JB; jb++){
        float acc[64];
        #pragma unroll
        for(int j = 0; j < 64; j++) acc[j] = 0.f;
        for(int k4 = 0; k4 < K/4; k4++){
            float4 xv = x4[k4];
            #pragma unroll
            for(int kk = 0; kk < 4; kk++){
                float xs_ = (kk==0)?xv.x:(kk==1)?xv.y:(kk==2)?xv.z:xv.w;
                const float4* wrow = (const float4*)&Ws[(k4*4+kk)*J + jb*64];
                #pragma unroll
                for(int j4 = 0; j4 < 16; j4++){
                    float4 w = wrow[j4];
                    acc[4*j4+0] = fmaf(xs_, w.x, acc[4*j4+0]);
                    acc[4*j4+1] = fmaf(xs_, w.y, acc[4*j4+1]);
                    acc[4*j4+2] = fmaf(xs_, w.z, acc[4*j4+2]);
                    acc[4*j4+3] = fmaf(xs_, w.w, acc[4*j4+3]);
                }
            }
        }
        float4* o4 = (float4*)(out + (size_t)n*J + jb*64);
        #pragma unroll
        for(int j4 = 0; j4 < 16; j4++){
            float4 v;
            float* vp = (float*)&v;
            #pragma unroll
            for(int c = 0; c < 4; c++){
                int j = 4*j4 + c;
                float t = acc[j];
                if(FOLD) t = t*Fs[jb*64+j] + Fs[J + jb*64 + j];
                if(RELU) t = fmaxf(t, 0.f);
                vp[c] = t;
            }
            o4[j4] = v;
        }
    }
}

// ---------------- GCN aggregation: relu(sum_in + self + b) ----------------
__global__ void __launch_bounds__(256) k_agg(const float* __restrict__ hw,
                                             const int* __restrict__ starts,
                                             const int* __restrict__ deg,
                                             const int* __restrict__ csr,
                                             const float* __restrict__ dinv,
                                             const float* __restrict__ bias,
                                             float* __restrict__ out){
    int t = threadIdx.x, w = t>>6, f = t&63;
    int n = blockIdx.x*4 + w;
    int s = starts[n], d = deg[n];
    float acc = 0.f;
    int i = 0;
    for(; i+1 < d; i += 2){
        int r0 = csr[s+i], r1 = csr[s+i+1];
        float v0 = hw[(size_t)r0*64 + f];
        float v1 = hw[(size_t)r1*64 + f];
        acc += v0 * dinv[r0];
        acc += v1 * dinv[r1];
    }
    if(i < d){
        int r0 = csr[s+i];
        acc += hw[(size_t)r0*64 + f] * dinv[r0];
    }
    float dn = dinv[n];
    float self = hw[(size_t)n*64 + f];
    float v = acc*dn + self*dn*dn + bias[f];
    out[(size_t)n*64 + f] = fmaxf(v, 0.f);
}

// ---------------- edge predictor (factorized): thread-per-edge ----------------
// z = sum_j relu(preA[r][j] + preB[c][j]) * w2[j] + b2 ; out = sigmoid(z)
__global__ void __launch_bounds__(256) k_edge2(const float* __restrict__ pre,
                                               const int* __restrict__ row,
                                               const int* __restrict__ col,
                                               const float* __restrict__ w2,
                                               const float* __restrict__ b2,
                                               float* __restrict__ out){
    __shared__ float w2s[64];
    __shared__ float b2s;
    if(threadIdx.x < 64) w2s[threadIdx.x] = w2[threadIdx.x];
    if(threadIdx.x == 64) b2s = b2[0];
    __syncthreads();
    int e = blockIdx.x*256 + threadIdx.x;
    if(e >= NE) return;
    int r = row[e], c = col[e];
    const float4* pa = (const float4*)(pre + (size_t)r*128);
    const float4* pb = (const float4*)(pre + (size_t)c*128 + 64);
    const float4* wv = (const float4*)w2s;
    float z = 0.f;
    #pragma unroll
    for(int q = 0; q < 16; q++){
        float4 a = pa[q], b = pb[q], w = wv[q];
        z += fmaxf(a.x + b.x, 0.f) * w.x;
        z += fmaxf(a.y + b.y, 0.f) * w.y;
        z += fmaxf(a.z + b.z, 0.f) * w.z;
        z += fmaxf(a.w + b.w, 0.f) * w.w;
    }
    z += b2s;
    out[e] = 1.f / (1.f + __expf(-z));
}

// ---------------- launch ----------------

extern "C" void kernel_launch(void* const* d_in, const int* in_sizes, int n_in,
                              void* d_out, int out_size, void* d_ws, size_t ws_size,
                              hipStream_t stream){
    const float* x   = (const float*)d_in[0];
    const int* ei    = (const int*)d_in[1];
    const int* row   = ei;
    const int* col   = ei + NE;
    const float* encW = (const float*)d_in[2],  *encB = (const float*)d_in[3];
    const float* encG = (const float*)d_in[4],  *encBe= (const float*)d_in[5];
    const float* encM = (const float*)d_in[6],  *encV = (const float*)d_in[7];
    const float* c1W  = (const float*)d_in[8],  *c1b  = (const float*)d_in[9];
    const float* c2W  = (const float*)d_in[10], *c2b  = (const float*)d_in[11];
    const float* ep1W = (const float*)d_in[12], *ep1b = (const float*)d_in[13];
    const float* epG  = (const float*)d_in[14], *epBe = (const float*)d_in[15];
    const float* epM  = (const float*)d_in[16], *epV  = (const float*)d_in[17];
    const float* ep2W = (const float*)d_in[18], *ep2b = (const float*)d_in[19];

    char* wsc = (char*)d_ws;
    size_t o = 0;
    auto alloc = [&](size_t bytes)->void*{
        void* p = wsc + o; o += (bytes + 255) & ~(size_t)255; return p;
    };
    int*   deg     = (int*)  alloc((size_t)NN*4);
    int*   starts  = (int*)  alloc((size_t)NN*4);
    int*   cursor  = (int*)  alloc((size_t)NN*4);
    int*   bsum    = (int*)  alloc(1024*4);
    int*   csr     = (int*)  alloc((size_t)NE*4);
    float* dinv    = (float*)alloc((size_t)NN*4);
    float* foldEnc = (float*)alloc(128*4);
    float* foldPre = (float*)alloc(256*4);
    float* bufA    = (float*)alloc((size_t)NN*64*4);
    float* bufB    = (float*)alloc((size_t)NN*64*4);
    // pre[N,128] aliases bufA+bufB (both dead by the time pre is written)
    float* pre     = bufA;
    // total ~59 MB of d_ws

    float* outp = (float*)d_out;               // [NN*64] node emb | [NE] edge preds
    float* node_out = outp;
    float* edge_out = outp + (size_t)NN*64;

    hipMemsetAsync(deg, 0, (size_t)NN*4, stream);
    k_count<<<(NE+255)/256, 256, 0, stream>>>(col, deg);
    k_bsum <<<NB_SCAN,      256, 0, stream>>>(deg, bsum);
    k_top  <<<1,            512, 0, stream>>>(bsum);
    k_scan <<<NB_SCAN,      256, 0, stream>>>(deg, bsum, starts, cursor, dinv);
    k_fill <<<(NE+255)/256, 256, 0, stream>>>(row, col, cursor, csr);
    k_const<<<1, 64, 0, stream>>>(encB, encG, encBe, encM, encV,
                                  ep1b, epG, epBe, epM, epV, foldEnc, foldPre);

    // encoder: relu(bn(x @ encW + b))
    k_gemv<128,1,false,true,true><<<NB_SCAN, 256, 0, stream>>>(x, encW, foldEnc, bufA);

    // conv1
    k_gemv<64,1,false,false,false><<<NB_SCAN, 256, 0, stream>>>(bufA, c1W, nullptr, bufB);
    k_agg  <<<NN/4, 256, 0, stream>>>(bufB, starts, deg, csr, dinv, c1b, bufA);

    // conv2
    k_gemv<64,1,false,false,false><<<NB_SCAN, 256, 0, stream>>>(bufA, c2W, nullptr, bufB);
    k_agg  <<<NN/4, 256, 0, stream>>>(bufB, starts, deg, csr, dinv, c2b, node_out);

    // edge predictor precompute: pre[n] = [s*(h@W1top)+cst , s*(h@W1bot)]
    k_gemv<64,2,true,true,false><<<NB_SCAN, 256, 0, stream>>>(node_out, ep1W, foldPre, pre);

    // per-edge: sigmoid(sum relu(preA[r]+preB[c])*w2 + b2)
    k_edge2<<<NE/256, 256, 0, stream>>>(pre, row, col, ep2W, ep2b, edge_out);
}

// Round 4
// 711.134 us; speedup vs baseline: 3.1320x; 1.4078x over previous
//
#include <hip/hip_runtime.h>
#include <hip/hip_bf16.h>

#define NN 100000
#define NE 1600000
#define FIN 128
#define HD 64
#define NB_SCAN 391   // ceil(NN/256)

typedef unsigned int  uint32;
typedef unsigned short ushort16;

__device__ __forceinline__ unsigned short f2bs(float f){   // fp32 -> bf16 bits (RNE)
    uint32 u = __float_as_uint(f);
    u += 0x7fffu + ((u >> 16) & 1u);
    return (unsigned short)(u >> 16);
}
__device__ __forceinline__ float bs2f(unsigned short s){   // bf16 bits -> fp32
    return __uint_as_float((uint32)s << 16);
}

// ---------------- degree / CSR build ----------------

__global__ void k_count(const int* __restrict__ col, int* __restrict__ deg){
    int e = blockIdx.x*256 + threadIdx.x;
    if(e < NE) atomicAdd(&deg[col[e]], 1);
}

__global__ void k_bsum(const int* __restrict__ deg, int* __restrict__ bsum){
    __shared__ int r[256];
    int t = threadIdx.x; int i = blockIdx.x*256 + t;
    r[t] = (i < NN) ? deg[i] : 0;
    __syncthreads();
    for(int off=128; off>0; off>>=1){ if(t<off) r[t]+=r[t+off]; __syncthreads(); }
    if(t==0) bsum[blockIdx.x] = r[0];
}

__global__ void k_top(int* __restrict__ bsum){
    __shared__ int s[512];
    int t = threadIdx.x;
    int v = (t < NB_SCAN) ? bsum[t] : 0;
    s[t] = v; __syncthreads();
    for(int off=1; off<512; off<<=1){
        int a = (t>=off)? s[t-off] : 0;
        __syncthreads();
        s[t] += a;
        __syncthreads();
    }
    if(t < NB_SCAN) bsum[t] = s[t] - v;   // exclusive scan of block sums
}

__global__ void k_scan(const int* __restrict__ deg, const int* __restrict__ bsum,
                       int* __restrict__ starts, int* __restrict__ cursor,
                       float* __restrict__ dinv){
    __shared__ int s[256];
    int t = threadIdx.x; int i = blockIdx.x*256 + t;
    int d = (i<NN)? deg[i] : 0;
    s[t] = d; __syncthreads();
    for(int off=1; off<256; off<<=1){
        int a = (t>=off)? s[t-off] : 0;
        __syncthreads();
        s[t] += a;
        __syncthreads();
    }
    if(i < NN){
        int st = bsum[blockIdx.x] + s[t] - d;   // exclusive
        starts[i] = st; cursor[i] = st;
        dinv[i] = rsqrtf((float)(d + 1));       // +1 self-loop
    }
}

__global__ void k_fill(const int* __restrict__ row, const int* __restrict__ col,
                       int* __restrict__ cursor, int* __restrict__ csr){
    int e = blockIdx.x*256 + threadIdx.x;
    if(e < NE){
        int c = col[e];
        int p = atomicAdd(&cursor[c], 1);
        csr[p] = row[e];
    }
}

// ---------------- BN constant folding ----------------
__global__ void k_const(const float* __restrict__ encB, const float* __restrict__ encG,
                        const float* __restrict__ encBe, const float* __restrict__ encM,
                        const float* __restrict__ encV,
                        const float* __restrict__ ep1b, const float* __restrict__ epG,
                        const float* __restrict__ epBe, const float* __restrict__ epM,
                        const float* __restrict__ epV,
                        float* __restrict__ foldEnc, float* __restrict__ foldPre){
    int j = threadIdx.x;
    if(j < 64){
        float s = encG[j]*rsqrtf(encV[j]+1e-5f);
        foldEnc[j]      = s;
        foldEnc[64+j]   = (encB[j]-encM[j])*s + encBe[j];
        float sp = epG[j]*rsqrtf(epV[j]+1e-5f);
        foldPre[j]      = sp;
        foldPre[64+j]   = sp;
        foldPre[128+j]  = sp*(ep1b[j]-epM[j]) + epBe[j];
        foldPre[192+j]  = 0.f;
    }
}

// ---------------- generic GEMV: thread-per-node, W staged in LDS ----------------
// out[n][jb*64+j] = epilogue( sum_k in[n][k] * W[k][jb*64+j] )
// PREMAP: W source is ep1W [128,64]; logical W[k][j] = j<64 ? ep1W[k][j] : ep1W[64+k][j-64]
template<int K, int JB, bool PREMAP, bool FOLD, bool RELU, bool OBF16>
__global__ void __launch_bounds__(256) k_gemv(const float* __restrict__ in,
                                              const float* __restrict__ W,
                                              const float* __restrict__ fold,
                                              void* __restrict__ outv){
    __shared__ float Ws[K*JB*64];
    __shared__ float Fs[2*JB*64];
    const int J = JB*64;
    for(int idx = threadIdx.x; idx < K*J; idx += 256){
        if(PREMAP){
            int k = idx / J, j = idx % J;   // J=128 here
            Ws[idx] = (j < 64) ? W[k*64 + j] : W[(64+k)*64 + (j-64)];
        } else {
            Ws[idx] = W[idx];
        }
    }
    if(FOLD){
        for(int idx = threadIdx.x; idx < 2*J; idx += 256) Fs[idx] = fold[idx];
    }
    __syncthreads();
    int n = blockIdx.x*256 + threadIdx.x;
    if(n >= NN) return;
    const float4* x4 = (const float4*)(in + (size_t)n*K);
    for(int jb = 0; jb < JB; jb++){
        float acc[64];
        #pragma unroll
        for(int j = 0; j < 64; j++) acc[j] = 0.f;
        for(int k4 = 0; k4 < K/4; k4++){
            float4 xv = x4[k4];
            #pragma unroll
            for(int kk = 0; kk < 4; kk++){
                float xs_ = (kk==0)?xv.x:(kk==1)?xv.y:(kk==2)?xv.z:xv.w;
                const float4* wrow = (const float4*)&Ws[(k4*4+kk)*J + jb*64];
                #pragma unroll
                for(int j4 = 0; j4 < 16; j4++){
                    float4 w = wrow[j4];
                    acc[4*j4+0] = fmaf(xs_, w.x, acc[4*j4+0]);
                    acc[4*j4+1] = fmaf(xs_, w.y, acc[4*j4+1]);
                    acc[4*j4+2] = fmaf(xs_, w.z, acc[4*j4+2]);
                    acc[4*j4+3] = fmaf(xs_, w.w, acc[4*j4+3]);
                }
            }
        }
        #pragma unroll
        for(int j4 = 0; j4 < 16; j4++){
            float vv[4];
            #pragma unroll
            for(int c = 0; c < 4; c++){
                int j = 4*j4 + c;
                float t = acc[j];
                if(FOLD) t = t*Fs[jb*64+j] + Fs[J + jb*64 + j];
                if(RELU) t = fmaxf(t, 0.f);
                vv[c] = t;
            }
            if(OBF16){
                ushort4 u;
                u.x = f2bs(vv[0]); u.y = f2bs(vv[1]);
                u.z = f2bs(vv[2]); u.w = f2bs(vv[3]);
                ((ushort4*)((unsigned short*)outv + (size_t)n*J + jb*64))[j4] = u;
            } else {
                float4 v;
                v.x = vv[0]; v.y = vv[1]; v.z = vv[2]; v.w = vv[3];
                ((float4*)((float*)outv + (size_t)n*J + jb*64))[j4] = v;
            }
        }
    }
}

// ---------------- GCN aggregation (bf16 hw): relu(sum_in + self + b) ----------------
__global__ void __launch_bounds__(256) k_agg(const unsigned short* __restrict__ hw,
                                             const int* __restrict__ starts,
                                             const int* __restrict__ deg,
                                             const int* __restrict__ csr,
                                             const float* __restrict__ dinv,
                                             const float* __restrict__ bias,
                                             float* __restrict__ out){
    int t = threadIdx.x, w = t>>6, f = t&63;
    int n = blockIdx.x*4 + w;
    int s = starts[n], d = deg[n];
    float acc = 0.f;
    int i = 0;
    for(; i+3 < d; i += 4){                 // 4-way unroll for outstanding gathers
        int r0 = csr[s+i],   r1 = csr[s+i+1];
        int r2 = csr[s+i+2], r3 = csr[s+i+3];
        float v0 = bs2f(hw[(size_t)r0*64 + f]);
        float v1 = bs2f(hw[(size_t)r1*64 + f]);
        float v2 = bs2f(hw[(size_t)r2*64 + f]);
        float v3 = bs2f(hw[(size_t)r3*64 + f]);
        acc = fmaf(v0, dinv[r0], acc);
        acc = fmaf(v1, dinv[r1], acc);
        acc = fmaf(v2, dinv[r2], acc);
        acc = fmaf(v3, dinv[r3], acc);
    }
    for(; i < d; i++){
        int r0 = csr[s+i];
        acc = fmaf(bs2f(hw[(size_t)r0*64 + f]), dinv[r0], acc);
    }
    float dn = dinv[n];
    float self = bs2f(hw[(size_t)n*64 + f]);
    float v = acc*dn + self*dn*dn + bias[f];
    out[(size_t)n*64 + f] = fmaxf(v, 0.f);
}

// ---------------- edge predictor (factorized, bf16 pre): thread-per-edge ----------------
// z = sum_j relu(preA[r][j] + preB[c][j]) * w2[j] + b2 ; out = sigmoid(z)
__global__ void __launch_bounds__(256) k_edge2(const unsigned short* __restrict__ pre,
                                               const int* __restrict__ row,
                                               const int* __restrict__ col,
                                               const float* __restrict__ w2,
                                               const float* __restrict__ b2,
                                               float* __restrict__ out){
    __shared__ float w2s[64];
    __shared__ float b2s;
    if(threadIdx.x < 64) w2s[threadIdx.x] = w2[threadIdx.x];
    if(threadIdx.x == 64) b2s = b2[0];
    __syncthreads();
    int e = blockIdx.x*256 + threadIdx.x;
    if(e >= NE) return;
    int r = row[e], c = col[e];
    const uint4* pa = (const uint4*)(pre + (size_t)r*128);        // A half: 128B
    const uint4* pb = (const uint4*)(pre + (size_t)c*128 + 64);   // B half: 128B
    float z = 0.f;
    #pragma unroll
    for(int q = 0; q < 4; q++){                  // 4 x uint4 = 32 bf16 pairs... 8 bf16 each
        uint4 ua = pa[q], ub = pb[q];
        const uint32* au = (const uint32*)&ua;
        const uint32* bu = (const uint32*)&ub;
        #pragma unroll
        for(int u = 0; u < 4; u++){
            uint32 a = au[u], b = bu[u];
            float alo = __uint_as_float(a << 16);
            float ahi = __uint_as_float(a & 0xffff0000u);
            float blo = __uint_as_float(b << 16);
            float bhi = __uint_as_float(b & 0xffff0000u);
            int j = q*8 + u*2;
            z = fmaf(fmaxf(alo + blo, 0.f), w2s[j],   z);
            z = fmaf(fmaxf(ahi + bhi, 0.f), w2s[j+1], z);
        }
    }
    z += b2s;
    out[e] = 1.f / (1.f + __expf(-z));
}

// ---------------- launch ----------------

extern "C" void kernel_launch(void* const* d_in, const int* in_sizes, int n_in,
                              void* d_out, int out_size, void* d_ws, size_t ws_size,
                              hipStream_t stream){
    const float* x   = (const float*)d_in[0];
    const int* ei    = (const int*)d_in[1];
    const int* row   = ei;
    const int* col   = ei + NE;
    const float* encW = (const float*)d_in[2],  *encB = (const float*)d_in[3];
    const float* encG = (const float*)d_in[4],  *encBe= (const float*)d_in[5];
    const float* encM = (const float*)d_in[6],  *encV = (const float*)d_in[7];
    const float* c1W  = (const float*)d_in[8],  *c1b  = (const float*)d_in[9];
    const float* c2W  = (const float*)d_in[10], *c2b  = (const float*)d_in[11];
    const float* ep1W = (const float*)d_in[12], *ep1b = (const float*)d_in[13];
    const float* epG  = (const float*)d_in[14], *epBe = (const float*)d_in[15];
    const float* epM  = (const float*)d_in[16], *epV  = (const float*)d_in[17];
    const float* ep2W = (const float*)d_in[18], *ep2b = (const float*)d_in[19];

    char* wsc = (char*)d_ws;
    size_t o = 0;
    auto alloc = [&](size_t bytes)->void*{
        void* p = wsc + o; o += (bytes + 255) & ~(size_t)255; return p;
    };
    int*   deg     = (int*)  alloc((size_t)NN*4);
    int*   starts  = (int*)  alloc((size_t)NN*4);
    int*   cursor  = (int*)  alloc((size_t)NN*4);
    int*   bsum    = (int*)  alloc(1024*4);
    int*   csr     = (int*)  alloc((size_t)NE*4);
    float* dinv    = (float*)alloc((size_t)NN*4);
    float* foldEnc = (float*)alloc(128*4);
    float* foldPre = (float*)alloc(256*4);
    float* bufA    = (float*)alloc((size_t)NN*64*4);   // fp32 h buffer
    unsigned short* bufB = (unsigned short*)alloc((size_t)NN*64*2);  // bf16 hw buffer
    // pre[N,128] bf16 (25.6 MB) aliases bufA (dead after conv2 gemv)
    unsigned short* preb = (unsigned short*)bufA;

    float* outp = (float*)d_out;               // [NN*64] node emb | [NE] edge preds
    float* node_out = outp;
    float* edge_out = outp + (size_t)NN*64;

    hipMemsetAsync(deg, 0, (size_t)NN*4, stream);
    k_count<<<(NE+255)/256, 256, 0, stream>>>(col, deg);
    k_bsum <<<NB_SCAN,      256, 0, stream>>>(deg, bsum);
    k_top  <<<1,            512, 0, stream>>>(bsum);
    k_scan <<<NB_SCAN,      256, 0, stream>>>(deg, bsum, starts, cursor, dinv);
    k_fill <<<(NE+255)/256, 256, 0, stream>>>(row, col, cursor, csr);
    k_const<<<1, 64, 0, stream>>>(encB, encG, encBe, encM, encV,
                                  ep1b, epG, epBe, epM, epV, foldEnc, foldPre);

    // encoder: relu(bn(x @ encW + b)) -> fp32 bufA
    k_gemv<128,1,false,true,true,false><<<NB_SCAN, 256, 0, stream>>>(x, encW, foldEnc, bufA);

    // conv1: hw bf16 -> aggregate fp32
    k_gemv<64,1,false,false,false,true><<<NB_SCAN, 256, 0, stream>>>(bufA, c1W, nullptr, bufB);
    k_agg  <<<NN/4, 256, 0, stream>>>(bufB, starts, deg, csr, dinv, c1b, bufA);

    // conv2
    k_gemv<64,1,false,false,false,true><<<NB_SCAN, 256, 0, stream>>>(bufA, c2W, nullptr, bufB);
    k_agg  <<<NN/4, 256, 0, stream>>>(bufB, starts, deg, csr, dinv, c2b, node_out);

    // edge predictor precompute -> bf16 pre
    k_gemv<64,2,true,true,false,true><<<NB_SCAN, 256, 0, stream>>>(node_out, ep1W, foldPre, preb);

    // per-edge: sigmoid(sum relu(preA[r]+preB[c])*w2 + b2)
    k_edge2<<<NE/256, 256, 0, stream>>>(preb, row, col, ep2W, ep2b, edge_out);
}